// Round 1
// baseline (16.500 us; speedup 1.0000x reference)
//
#include <hip/hip_runtime.h>

// DenseMLPQMatrixDecoder: per-vocab 4x4 CTMC rate matrix from an MLP, then
// stationary-ish probs via expm(1000*Q), broadcast across S sites.
// Q depends only on v, so expm is computed once per v (1024 matrices) and
// the [V,S,A] output is a pure broadcast of row 0.

namespace {

constexpr int kA = 4;
constexpr int kD = 8;
constexpr int kW = 16;
constexpr int kV = 1024;
constexpr int kS = 1024;
constexpr int kSquarings = 14;          // 2^14 = 16384
constexpr int kTaylorOrder = 8;         // tau*||Q|| ~ 0.12 -> trunc err ~1e-14

__global__ void q_expm_kernel(const float* __restrict__ emb,
                              const float* __restrict__ W0,
                              const float* __restrict__ b0,
                              const float* __restrict__ W1,
                              const float* __restrict__ b1,
                              const float* __restrict__ Wout,
                              const float* __restrict__ bout,
                              float4* __restrict__ row0) {
  const int v = blockIdx.x * blockDim.x + threadIdx.x;
  if (v >= kV) return;

  // ---- MLP: D -> W -> W -> A*A (ReLU hidden) ----
  float x[kD];
#pragma unroll
  for (int d = 0; d < kD; ++d) x[d] = emb[v * kD + d];

  float h0[kW];
#pragma unroll
  for (int j = 0; j < kW; ++j) {
    float acc = b0[j];
#pragma unroll
    for (int d = 0; d < kD; ++d) acc = fmaf(x[d], W0[d * kW + j], acc);
    h0[j] = fmaxf(acc, 0.0f);
  }

  float h1[kW];
#pragma unroll
  for (int j = 0; j < kW; ++j) {
    float acc = b1[j];
#pragma unroll
    for (int k = 0; k < kW; ++k) acc = fmaf(h0[k], W1[k * kW + j], acc);
    h1[j] = fmaxf(acc, 0.0f);
  }

  float l[kA * kA];
#pragma unroll
  for (int j = 0; j < kA * kA; ++j) {
    float acc = bout[j];
#pragma unroll
    for (int k = 0; k < kW; ++k) acc = fmaf(h1[k], Wout[k * (kA * kA) + j], acc);
    l[j] = acc;
  }

  // ---- Build M = tau * Q, Q = P - I, P = per-row off-diagonal softmax ----
  // (max-subtraction before exp is exact: normalization is shift-invariant)
  const double tau = 1000.0 / (double)(1 << kSquarings);
  double M[kA][kA];
#pragma unroll
  for (int i = 0; i < kA; ++i) {
    float m = -3.0e38f;
#pragma unroll
    for (int j = 0; j < kA; ++j)
      if (j != i) m = fmaxf(m, l[i * kA + j]);
    float e[kA];
    float ssum = 0.0f;
#pragma unroll
    for (int j = 0; j < kA; ++j) {
      e[j] = (j == i) ? 0.0f : expf(l[i * kA + j] - m);
      ssum += e[j];
    }
    const float inv = 1.0f / ssum;
#pragma unroll
    for (int j = 0; j < kA; ++j)
      M[i][j] = tau * ((j == i) ? -1.0 : (double)(e[j] * inv));
  }

  // ---- expm via order-8 Taylor (Horner) + 14 squarings, all fp64 ----
  double T[kA][kA];
#pragma unroll
  for (int i = 0; i < kA; ++i)
#pragma unroll
    for (int j = 0; j < kA; ++j) T[i][j] = (i == j) ? 1.0 : 0.0;

#pragma unroll
  for (int k = kTaylorOrder; k >= 1; --k) {
    double U[kA][kA];
#pragma unroll
    for (int i = 0; i < kA; ++i)
#pragma unroll
      for (int j = 0; j < kA; ++j) {
        double acc = 0.0;
#pragma unroll
        for (int p = 0; p < kA; ++p) acc = fma(M[i][p], T[p][j], acc);
        U[i][j] = acc;
      }
    const double rk = 1.0 / (double)k;
#pragma unroll
    for (int i = 0; i < kA; ++i)
#pragma unroll
      for (int j = 0; j < kA; ++j)
        T[i][j] = ((i == j) ? 1.0 : 0.0) + U[i][j] * rk;
  }

  for (int t = 0; t < kSquarings; ++t) {
    double U[kA][kA];
#pragma unroll
    for (int i = 0; i < kA; ++i)
#pragma unroll
      for (int j = 0; j < kA; ++j) {
        double acc = 0.0;
#pragma unroll
        for (int p = 0; p < kA; ++p) acc = fma(T[i][p], T[p][j], acc);
        U[i][j] = acc;
      }
#pragma unroll
    for (int i = 0; i < kA; ++i)
#pragma unroll
      for (int j = 0; j < kA; ++j) T[i][j] = U[i][j];
  }

  row0[v] = make_float4((float)T[0][0], (float)T[0][1],
                        (float)T[0][2], (float)T[0][3]);
}

// out[v][s][:] = row0[v][:]; one float4 store per (v,s) pair, coalesced.
__global__ void bcast_kernel(const float4* __restrict__ row0,
                             float4* __restrict__ out) {
  const int i = blockIdx.x * blockDim.x + threadIdx.x;  // over V*S (exact)
  out[i] = row0[i >> 10];                               // v = i / S, S = 1024
}

}  // namespace

extern "C" void kernel_launch(void* const* d_in, const int* in_sizes, int n_in,
                              void* d_out, int out_size, void* d_ws,
                              size_t ws_size, hipStream_t stream) {
  const float* emb  = (const float*)d_in[0];
  // d_in[1] = site_positions_SxC: unused (output is independent of positions)
  const float* W0   = (const float*)d_in[2];
  const float* b0   = (const float*)d_in[3];
  const float* W1   = (const float*)d_in[4];
  const float* b1   = (const float*)d_in[5];
  const float* Wout = (const float*)d_in[6];
  const float* bout = (const float*)d_in[7];

  float4* row0 = (float4*)d_ws;  // kV float4 = 16 KB scratch

  q_expm_kernel<<<kV / 64, 64, 0, stream>>>(emb, W0, b0, W1, b1, Wout, bout,
                                            row0);
  bcast_kernel<<<(kV * kS) / 256, 256, 0, stream>>>(row0, (float4*)d_out);
}